// Round 16
// baseline (99.896 us; speedup 1.0000x reference)
//
#include <hip/hip_runtime.h>
#include <hip/hip_fp16.h>

#define D 64
#define KP 50          // neighbors per row
#define NIT 10000      // R row stride

#define RFL __builtin_amdgcn_readfirstlane

typedef _Float16 half8 __attribute__((ext_vector_type(8)));
typedef _Float16 h2 __attribute__((ext_vector_type(2)));
typedef float floatx4 __attribute__((ext_vector_type(4)));

__device__ inline float rlanef(float v, int l) {
  return __int_as_float(__builtin_amdgcn_readlane(__float_as_int(v), l));
}

// ---------------- MFMA fragment helpers (16x16x32 f16) --------------------------
// A-frag: lane l holds A[m = l&15][k = kc*32 + 8*(l>>4) + j], j=0..7  (fp32 src)
__device__ inline half8 loadA_f32(const float* __restrict__ src, int kc,
                                  int lane) {
  const float* p = src + (size_t)(lane & 15) * D + kc * 32 + 8 * (lane >> 4);
  float4 lo = *(const float4*)p;
  float4 hi = *(const float4*)(p + 4);
  half8 a;
  a[0] = (_Float16)lo.x; a[1] = (_Float16)lo.y;
  a[2] = (_Float16)lo.z; a[3] = (_Float16)lo.w;
  a[4] = (_Float16)hi.x; a[5] = (_Float16)hi.y;
  a[6] = (_Float16)hi.z; a[7] = (_Float16)hi.w;
  return a;
}

// B-frag: lane l holds B[k = kc*32 + 8*(l>>4)+j][n = 16*t + (l&15)]  (fp32 W, ld=D)
__device__ inline half8 loadB_f32(const float* __restrict__ W, int kc, int t,
                                  int lane) {
  const float* p =
      W + (size_t)(kc * 32 + 8 * (lane >> 4)) * D + 16 * t + (lane & 15);
  half8 b;
#pragma unroll
  for (int j = 0; j < 8; ++j) b[j] = (_Float16)p[(size_t)j * D];
  return b;
}

// ---------------- wave-level helpers (no LDS, no barriers) ----------------------
// score = sum_d relu(xa[d] + ia[d]) * w2[d]
// xa: per-lane fp16 row; ia/w2: wave-uniform packed fp16 (s_load); fp32 accum.
__device__ inline float score_row_pk(const __half* __restrict__ xa,
                                     const __half* __restrict__ ia,
                                     const __half* __restrict__ w2) {
  float p = 0.f;
  const h2 hz = {(_Float16)0.f, (_Float16)0.f};
#pragma unroll
  for (int j = 0; j < D; j += 8) {
    float4 q = *(const float4*)&xa[j];  // 8 halves of this lane's row
    const h2* x2 = (const h2*)&q;
#pragma unroll
    for (int m = 0; m < 4; ++m) {
      const h2 iv = *(const h2*)&ia[j + 2 * m];  // uniform
      const h2 wv = *(const h2*)&w2[j + 2 * m];  // uniform
      h2 t = x2[m] + iv;                          // v_pk_add_f16
      t = __builtin_elementwise_max(t, hz);       // v_pk_max_f16
#if __has_builtin(__builtin_amdgcn_fdot2)
      p = __builtin_amdgcn_fdot2(t, wv, p, false);  // v_dot2_f32_f16
#else
      p = fmaf((float)t[0], (float)wv[0], p);
      p = fmaf((float)t[1], (float)wv[1], p);
#endif
    }
  }
  return p;
}

__device__ inline float softmax50(float val, int lane) {
  val = (lane < KP) ? val : -1e30f;
  float m = val;
#pragma unroll
  for (int o = 1; o < 64; o <<= 1) m = fmaxf(m, __shfl_xor(m, o, 64));
  float e = (lane < KP) ? __expf(val - m) : 0.f;
  float s = e;
#pragma unroll
  for (int o = 1; o < 64; o <<= 1) s += __shfl_xor(s, o, 64);
  return e / s;
}

__device__ inline float wsum_rows_h(float a, int ix,
                                    const __half* __restrict__ T, int lane) {
  float v0 = 0.f, v1 = 0.f;
#pragma unroll 10
  for (int k = 0; k < KP; k += 2) {
    const int i0 = __builtin_amdgcn_readlane(ix, k);
    const int i1 = __builtin_amdgcn_readlane(ix, k + 1);
    const float a0 = rlanef(a, k);
    const float a1 = rlanef(a, k + 1);
    v0 = fmaf(a0, (float)T[(size_t)i0 * 128 + 64 + lane], v0);
    v1 = fmaf(a1, (float)T[(size_t)i1 * 128 + 64 + lane], v1);
  }
  return v0 + v1;
}

template <bool RELU>
__device__ inline float mv64b(float vin, const float* __restrict__ W,
                              const float* __restrict__ bias, int lane) {
  float acc = bias[lane];
#pragma unroll 8
  for (int j = 0; j < D; ++j)
    acc = fmaf(rlanef(vin, j), W[j * D + lane], acc);
  return RELU ? fmaxf(acc, 0.f) : acc;
}

__device__ inline float mv128b(float lo, float hi, const float* __restrict__ W,
                               const float* __restrict__ bias, int lane) {
  float acc = bias[lane];
#pragma unroll 8
  for (int j = 0; j < D; ++j)
    acc = fmaf(rlanef(lo, j), W[j * D + lane], acc);
#pragma unroll 8
  for (int j = 0; j < D; ++j)
    acc = fmaf(rlanef(hi, j), W[(D + j) * D + lane], acc);
  return fmaxf(acc, 0.f);
}

// ---------------- fused MFMA table kernel ---------------------------------------
// grid = 2 * (NU/16) single-wave blocks.
//  s=0: item gate -> XXA5 rows + UAth     s=1: user gate -> FFA5 rows + IAuh,SAuh
//  s=1,blk=0 additionally converts Wa2 vectors to fp16 (W2h[0..2]).
#define LSTR 72  // padded LDS row stride in halves (144B)

__global__ __launch_bounds__(64) void k_tabs(
    const float* __restrict__ item_emb, const float* __restrict__ user_emb,
    const float* __restrict__ op_emb, const float* __restrict__ ia_Wg,
    const float* __restrict__ ia_bg, const float* __restrict__ ua_Wg,
    const float* __restrict__ ua_bg, const float* __restrict__ ia_Wa1,
    const float* __restrict__ ia_ba1, const float* __restrict__ sa_Wa1,
    const float* __restrict__ sa_ba1, const float* __restrict__ ua_Wa1,
    const float* __restrict__ ua_ba1, const float* __restrict__ ia_Wa2,
    const float* __restrict__ sa_Wa2, const float* __restrict__ ua_Wa2,
    __half* __restrict__ XXA5, __half* __restrict__ FFA5,
    __half* __restrict__ IAuh, __half* __restrict__ SAuh,
    __half* __restrict__ UAth, __half* __restrict__ W2h, int NU_) {
  __shared__ _Float16 ldsX[16 * LSTR];
  __shared__ _Float16 ldsA[16 * LSTR];
  const int lane = threadIdx.x;
  const int nbl = NU_ >> 4;
  const int s = blockIdx.x / nbl, blk = blockIdx.x % nbl;
  const int g0 = blk * 16;
  const int q = lane >> 4, p = lane & 15;

  const float* emb = s ? user_emb : item_emb;
  const float* Wg = s ? ua_Wg : ia_Wg;
  const float* bg = s ? ua_bg : ia_bg;
  const float* Wa = s ? ua_Wa1 : ia_Wa1;  // low 64 rows
  __half* dst = s ? FFA5 : XXA5;

  // A-fragments of this block's 16 emb rows (shared by all outputs)
  half8 a0 = loadA_f32(emb + (size_t)g0 * D, 0, lane);
  half8 a1 = loadA_f32(emb + (size_t)g0 * D, 1, lane);

  // ---- fused extra outputs (share a0/a1) ----
  if (s == 0) {
#pragma unroll
    for (int t = 0; t < 4; ++t) {
      floatx4 acc = {0.f, 0.f, 0.f, 0.f};
      half8 b0 = loadB_f32(ua_Wa1 + D * D, 0, t, lane);
      half8 b1 = loadB_f32(ua_Wa1 + D * D, 1, t, lane);
      acc = __builtin_amdgcn_mfma_f32_16x16x32_f16(a0, b0, acc, 0, 0, 0);
      acc = __builtin_amdgcn_mfma_f32_16x16x32_f16(a1, b1, acc, 0, 0, 0);
      const float bv = ua_ba1[16 * t + p];
#pragma unroll
      for (int i = 0; i < 4; ++i)
        UAth[(size_t)(g0 + 4 * q + i) * D + 16 * t + p] =
            __float2half(acc[i] + bv);
    }
  } else {
    if (blk == 0 && lane < D) {
      W2h[lane] = __float2half(ia_Wa2[lane]);
      W2h[64 + lane] = __float2half(sa_Wa2[lane]);
      W2h[128 + lane] = __float2half(ua_Wa2[lane]);
    }
#pragma unroll
    for (int t = 0; t < 4; ++t) {
      floatx4 acc = {0.f, 0.f, 0.f, 0.f};
      half8 b0 = loadB_f32(ia_Wa1 + D * D, 0, t, lane);
      half8 b1 = loadB_f32(ia_Wa1 + D * D, 1, t, lane);
      acc = __builtin_amdgcn_mfma_f32_16x16x32_f16(a0, b0, acc, 0, 0, 0);
      acc = __builtin_amdgcn_mfma_f32_16x16x32_f16(a1, b1, acc, 0, 0, 0);
      const float bv = ia_ba1[16 * t + p];
#pragma unroll
      for (int i = 0; i < 4; ++i)
        IAuh[(size_t)(g0 + 4 * q + i) * D + 16 * t + p] =
            __float2half(acc[i] + bv);
    }
#pragma unroll
    for (int t = 0; t < 4; ++t) {
      floatx4 acc = {0.f, 0.f, 0.f, 0.f};
      half8 b0 = loadB_f32(sa_Wa1 + D * D, 0, t, lane);
      half8 b1 = loadB_f32(sa_Wa1 + D * D, 1, t, lane);
      acc = __builtin_amdgcn_mfma_f32_16x16x32_f16(a0, b0, acc, 0, 0, 0);
      acc = __builtin_amdgcn_mfma_f32_16x16x32_f16(a1, b1, acc, 0, 0, 0);
      const float bv = sa_ba1[16 * t + p];
#pragma unroll
      for (int i = 0; i < 4; ++i)
        SAuh[(size_t)(g0 + 4 * q + i) * D + 16 * t + p] =
            __float2half(acc[i] + bv);
    }
  }

  // ---- opbg[r] = bg + op_emb[r] @ Wg_hi  (per-lane d = lane) ----
  float opbg[5];
#pragma unroll
  for (int r = 0; r < 5; ++r) opbg[r] = bg[lane];
  for (int j = 0; j < D; ++j) {
    const float w = Wg[(size_t)(D + j) * D + lane];
#pragma unroll
    for (int r = 0; r < 5; ++r) opbg[r] = fmaf(op_emb[r * D + j], w, opbg[r]);
  }

  // ---- base = emb16x64 @ Wg_lo ; preload Wa B-frags ----
  floatx4 base[4];
  half8 wa[4][2];
#pragma unroll
  for (int t = 0; t < 4; ++t) {
    base[t] = {0.f, 0.f, 0.f, 0.f};
    half8 b0 = loadB_f32(Wg, 0, t, lane);
    half8 b1 = loadB_f32(Wg, 1, t, lane);
    base[t] = __builtin_amdgcn_mfma_f32_16x16x32_f16(a0, b0, base[t], 0, 0, 0);
    base[t] = __builtin_amdgcn_mfma_f32_16x16x32_f16(a1, b1, base[t], 0, 0, 0);
    wa[t][0] = loadB_f32(Wa, 0, t, lane);
    wa[t][1] = loadB_f32(Wa, 1, t, lane);
  }

  for (int r = 0; r < 5; ++r) {
    __syncthreads();  // prior iteration's ldsX/ldsA readers done
#pragma unroll
    for (int t = 0; t < 4; ++t) {
      const float ob = __shfl(opbg[r], p + 16 * t, 64);
#pragma unroll
      for (int i = 0; i < 4; ++i)
        ldsX[(4 * q + i) * LSTR + 16 * t + p] =
            (_Float16)fmaxf(base[t][i] + ob, 0.f);
    }
    __syncthreads();  // ldsX committed before cross-lane reads
    half8 xa0 = *(const half8*)&ldsX[p * LSTR + 0 * 32 + 8 * q];
    half8 xa1 = *(const half8*)&ldsX[p * LSTR + 1 * 32 + 8 * q];
    floatx4 acc[4];
#pragma unroll
    for (int t = 0; t < 4; ++t) {
      acc[t] = {0.f, 0.f, 0.f, 0.f};
      acc[t] = __builtin_amdgcn_mfma_f32_16x16x32_f16(xa0, wa[t][0], acc[t], 0,
                                                      0, 0);
      acc[t] = __builtin_amdgcn_mfma_f32_16x16x32_f16(xa1, wa[t][1], acc[t], 0,
                                                      0, 0);
    }
#pragma unroll
    for (int t = 0; t < 4; ++t)
#pragma unroll
      for (int i = 0; i < 4; ++i)
        ldsA[(4 * q + i) * LSTR + 16 * t + p] = (_Float16)acc[t][i];
    __syncthreads();  // ldsA/ldsX committed before type-punned uint reads
    const uint32_t* srcbuf =
        (lane < 32) ? (const uint32_t*)ldsA : (const uint32_t*)ldsX;
    const int dl = lane & 31;
    for (int m = 0; m < 16; ++m) {
      const uint32_t val = srcbuf[m * (LSTR / 2) + dl];
      uint32_t* rowp = (uint32_t*)(dst + ((size_t)(g0 + m) * 5 + r) * 128);
      rowp[lane] = val;
    }
  }
}

// ---------------- h_I_all: one wave per user, zero barriers ---------------------
__global__ __launch_bounds__(256, 8) void k_hIall(
    const int* __restrict__ C, const int* __restrict__ Rm,
    const __half* __restrict__ XXA5, const __half* __restrict__ IAuh,
    const __half* __restrict__ W2h, const float* __restrict__ ia_W,
    const float* __restrict__ ia_b, const float* __restrict__ sa_Wa1,
    __half* __restrict__ HHA) {
  const int lane = threadIdx.x & 63;
  const int u = RFL(blockIdx.x * 4 + (threadIdx.x >> 6));
  const int kk = lane < KP ? lane : KP - 1;
  const int c = C[u * KP + kk];
  const int ix = c * 5 + Rm[(size_t)u * NIT + c];  // random HBM gather
  float sc = score_row_pk(XXA5 + (size_t)ix * 128, IAuh + (size_t)u * D, W2h);
  float a = softmax50(sc, lane);
  float v = wsum_rows_h(a, ix, XXA5, lane);
  float h = mv64b<true>(v, ia_W, ia_b, lane);
  float ha = 0.f;
#pragma unroll 8
  for (int j = 0; j < D; ++j)
    ha = fmaf(rlanef(h, j), sa_Wa1[j * D + lane], ha);
  HHA[(size_t)u * 128 + lane] = __float2half(ha);      // HA half (score)
  HHA[(size_t)u * 128 + 64 + lane] = __float2half(h);  // hI half (wsum/MLP)
}

// ---------------- batch: one wave per row, zero barriers (r13 serial form) ------
__global__ __launch_bounds__(256, 8) void k_batch(
    const int* __restrict__ user_idx, const int* __restrict__ item_idx,
    const int* __restrict__ Nn, const int* __restrict__ Bm,
    const int* __restrict__ Rm, const __half* __restrict__ HHA,
    const __half* __restrict__ FFA5, const __half* __restrict__ SAuh,
    const __half* __restrict__ UAth, const __half* __restrict__ W2h,
    const float* __restrict__ sa_W, const float* __restrict__ sa_b,
    const float* __restrict__ ua_W, const float* __restrict__ ua_b,
    const float* __restrict__ fu_W1, const float* __restrict__ fu_b1,
    const float* __restrict__ fu_W2, const float* __restrict__ fu_b2,
    const float* __restrict__ fu_W3, const float* __restrict__ fu_b3,
    const float* __restrict__ rp_W1, const float* __restrict__ rp_b1,
    const float* __restrict__ rp_W2, const float* __restrict__ rp_b2,
    const float* __restrict__ rp_W3, const float* __restrict__ rp_b3,
    float* __restrict__ out) {
  const int lane = threadIdx.x & 63;
  const int b = RFL(blockIdx.x * 4 + (threadIdx.x >> 6));
  const int u = RFL(user_idx[b]);
  const int it = RFL(item_idx[b]);
  const int kk = lane < KP ? lane : KP - 1;
  const int nix = Nn[u * KP + kk];
  const int bn = Bm[it * KP + kk];
  const int ix2 = bn * 5 + Rm[(size_t)bn * NIT + it];
  const float hIu = (float)HHA[(size_t)u * 128 + 64 + lane];
  // ---- phase S ----
  float sc =
      score_row_pk(HHA + (size_t)nix * 128, SAuh + (size_t)u * D, W2h + 64);
  float a = softmax50(sc, lane);
  float v = wsum_rows_h(a, nix, HHA, lane);
  float hS = mv64b<true>(v, sa_W, sa_b, lane);
  // ---- phase Z ----
  float sc2 =
      score_row_pk(FFA5 + (size_t)ix2 * 128, UAth + (size_t)it * D, W2h + 128);
  float a2 = softmax50(sc2, lane);
  float v2 = wsum_rows_h(a2, ix2, FFA5, lane);
  float z = mv64b<true>(v2, ua_W, ua_b, lane);
  // ---- fu MLP ----
  float h = mv128b(hIu, hS, fu_W1, fu_b1, lane);
  h = mv64b<true>(h, fu_W2, fu_b2, lane);
  h = mv64b<true>(h, fu_W3, fu_b3, lane);
  // ---- rp MLP ----
  float g = mv128b(h, z, rp_W1, rp_b1, lane);
  g = mv64b<true>(g, rp_W2, rp_b2, lane);
  float pp = g * rp_W3[lane];
#pragma unroll
  for (int o = 1; o < 64; o <<= 1) pp += __shfl_xor(pp, o, 64);
  if (lane == 0) out[b] = pp + rp_b3[0];
}

extern "C" void kernel_launch(void* const* d_in, const int* in_sizes, int n_in,
                              void* d_out, int out_size, void* d_ws,
                              size_t ws_size, hipStream_t stream) {
  const int* user_idx = (const int*)d_in[0];
  const int* item_idx = (const int*)d_in[1];
  const int* C = (const int*)d_in[2];
  const int* Nn = (const int*)d_in[3];
  const int* Bm = (const int*)d_in[4];
  const int* Rm = (const int*)d_in[5];
  const float* user_emb = (const float*)d_in[6];
  const float* item_emb = (const float*)d_in[7];
  const float* opinion_emb = (const float*)d_in[8];
  const float* ia_Wg = (const float*)d_in[9];
  const float* ia_bg = (const float*)d_in[10];
  const float* ua_Wg = (const float*)d_in[11];
  const float* ua_bg = (const float*)d_in[12];
  const float* ia_Wa1 = (const float*)d_in[13];
  const float* ia_ba1 = (const float*)d_in[14];
  const float* ia_Wa2 = (const float*)d_in[15];
  const float* ia_W = (const float*)d_in[17];
  const float* ia_b = (const float*)d_in[18];
  const float* sa_Wa1 = (const float*)d_in[19];
  const float* sa_ba1 = (const float*)d_in[20];
  const float* sa_Wa2 = (const float*)d_in[21];
  const float* sa_W = (const float*)d_in[23];
  const float* sa_b = (const float*)d_in[24];
  const float* ua_Wa1 = (const float*)d_in[25];
  const float* ua_ba1 = (const float*)d_in[26];
  const float* ua_Wa2 = (const float*)d_in[27];
  const float* ua_W = (const float*)d_in[29];
  const float* ua_b = (const float*)d_in[30];
  const float* fu_W1 = (const float*)d_in[31];
  const float* fu_b1 = (const float*)d_in[32];
  const float* fu_W2 = (const float*)d_in[33];
  const float* fu_b2 = (const float*)d_in[34];
  const float* rp_W1 = (const float*)d_in[35];
  const float* rp_b1 = (const float*)d_in[36];
  const float* rp_W2 = (const float*)d_in[37];
  const float* rp_b2 = (const float*)d_in[38];
  const float* fu_W3 = (const float*)d_in[39];
  const float* fu_b3 = (const float*)d_in[40];
  const float* rp_W3 = (const float*)d_in[41];
  const float* rp_b3 = (const float*)d_in[42];

  const int NU = in_sizes[6] / D;  // 10000 users
  const int B = in_sizes[0];       // 2048

  __half* XXA5 = (__half*)d_ws;                // NU*5*128 halves
  __half* FFA5 = XXA5 + (size_t)NU * 5 * 128;  // NU*5*128 halves
  __half* HHA = FFA5 + (size_t)NU * 5 * 128;   // NU*128 halves
  __half* IAuh = HHA + (size_t)NU * 128;       // NU*D halves
  __half* SAuh = IAuh + (size_t)NU * D;
  __half* UAth = SAuh + (size_t)NU * D;
  __half* W2h = UAth + (size_t)NU * D;         // 3*64 halves

  const int nbl = NU / 16;  // 625

  k_tabs<<<2 * nbl, 64, 0, stream>>>(
      item_emb, user_emb, opinion_emb, ia_Wg, ia_bg, ua_Wg, ua_bg, ia_Wa1,
      ia_ba1, sa_Wa1, sa_ba1, ua_Wa1, ua_ba1, ia_Wa2, sa_Wa2, ua_Wa2, XXA5,
      FFA5, IAuh, SAuh, UAth, W2h, NU);
  k_hIall<<<NU / 4, 256, 0, stream>>>(C, Rm, XXA5, IAuh, W2h, ia_W, ia_b,
                                      sa_Wa1, HHA);
  k_batch<<<B / 4, 256, 0, stream>>>(user_idx, item_idx, Nn, Bm, Rm, HHA, FFA5,
                                     SAuh, UAth, W2h, sa_W, sa_b, ua_W, ua_b,
                                     fu_W1, fu_b1, fu_W2, fu_b2, fu_W3, fu_b3,
                                     rp_W1, rp_b1, rp_W2, rp_b2, rp_W3, rp_b3,
                                     (float*)d_out);
}

// Round 17
// 90.933 us; speedup vs baseline: 1.0986x; 1.0986x over previous
//
#include <hip/hip_runtime.h>
#include <hip/hip_fp16.h>

#define D 64
#define KP 50          // neighbors per row
#define NIT 10000      // R row stride

#define RFL __builtin_amdgcn_readfirstlane

typedef _Float16 half8 __attribute__((ext_vector_type(8)));
typedef float floatx4 __attribute__((ext_vector_type(4)));

__device__ inline float rlanef(float v, int l) {
  return __int_as_float(__builtin_amdgcn_readlane(__float_as_int(v), l));
}

// ---------------- MFMA fragment helpers (16x16x32 f16) --------------------------
// A-frag: lane l holds A[m = l&15][k = kc*32 + 8*(l>>4) + j], j=0..7  (fp32 src)
__device__ inline half8 loadA_f32(const float* __restrict__ src, int kc,
                                  int lane) {
  const float* p = src + (size_t)(lane & 15) * D + kc * 32 + 8 * (lane >> 4);
  float4 lo = *(const float4*)p;
  float4 hi = *(const float4*)(p + 4);
  half8 a;
  a[0] = (_Float16)lo.x; a[1] = (_Float16)lo.y;
  a[2] = (_Float16)lo.z; a[3] = (_Float16)lo.w;
  a[4] = (_Float16)hi.x; a[5] = (_Float16)hi.y;
  a[6] = (_Float16)hi.z; a[7] = (_Float16)hi.w;
  return a;
}

// B-frag: lane l holds B[k = kc*32 + 8*(l>>4)+j][n = 16*t + (l&15)]  (fp32 W, ld=D)
__device__ inline half8 loadB_f32(const float* __restrict__ W, int kc, int t,
                                  int lane) {
  const float* p =
      W + (size_t)(kc * 32 + 8 * (lane >> 4)) * D + 16 * t + (lane & 15);
  half8 b;
#pragma unroll
  for (int j = 0; j < 8; ++j) b[j] = (_Float16)p[(size_t)j * D];
  return b;
}

// ---------------- wave-level helpers (no LDS, no barriers) ----------------------
__device__ inline float score_row_h(const __half* __restrict__ xa,
                                    const float* __restrict__ ia,
                                    const float* __restrict__ w2) {
  float p0 = 0.f, p1 = 0.f;
#pragma unroll
  for (int j = 0; j < D; j += 8) {
    float4 q = *(const float4*)&xa[j];
    const __half2* h2 = (const __half2*)&q;
#pragma unroll
    for (int m = 0; m < 4; ++m) {
      float2 f = __half22float2(h2[m]);
      p0 = fmaf(fmaxf(f.x + ia[j + 2 * m + 0], 0.f), w2[j + 2 * m + 0], p0);
      p1 = fmaf(fmaxf(f.y + ia[j + 2 * m + 1], 0.f), w2[j + 2 * m + 1], p1);
    }
  }
  return p0 + p1;
}

__device__ inline float softmax50(float val, int lane) {
  val = (lane < KP) ? val : -1e30f;
  float m = val;
#pragma unroll
  for (int o = 1; o < 64; o <<= 1) m = fmaxf(m, __shfl_xor(m, o, 64));
  float e = (lane < KP) ? __expf(val - m) : 0.f;
  float s = e;
#pragma unroll
  for (int o = 1; o < 64; o <<= 1) s += __shfl_xor(s, o, 64);
  return e / s;
}

__device__ inline float wsum_rows_h(float a, int ix,
                                    const __half* __restrict__ T, int lane) {
  float v0 = 0.f, v1 = 0.f;
#pragma unroll 10
  for (int k = 0; k < KP; k += 2) {
    const int i0 = __builtin_amdgcn_readlane(ix, k);
    const int i1 = __builtin_amdgcn_readlane(ix, k + 1);
    const float a0 = rlanef(a, k);
    const float a1 = rlanef(a, k + 1);
    v0 = fmaf(a0, (float)T[(size_t)i0 * 128 + 64 + lane], v0);
    v1 = fmaf(a1, (float)T[(size_t)i1 * 128 + 64 + lane], v1);
  }
  return v0 + v1;
}

template <bool RELU>
__device__ inline float mv64b(float vin, const float* __restrict__ W,
                              const float* __restrict__ bias, int lane) {
  float acc = bias[lane];
#pragma unroll 8
  for (int j = 0; j < D; ++j)
    acc = fmaf(rlanef(vin, j), W[j * D + lane], acc);
  return RELU ? fmaxf(acc, 0.f) : acc;
}

__device__ inline float mv128b(float lo, float hi, const float* __restrict__ W,
                               const float* __restrict__ bias, int lane) {
  float acc = bias[lane];
#pragma unroll 8
  for (int j = 0; j < D; ++j)
    acc = fmaf(rlanef(lo, j), W[j * D + lane], acc);
#pragma unroll 8
  for (int j = 0; j < D; ++j)
    acc = fmaf(rlanef(hi, j), W[(D + j) * D + lane], acc);
  return fmaxf(acc, 0.f);
}

// ---------------- fused MFMA table kernel ---------------------------------------
// grid = 2 * (NU/16) single-wave blocks.
//  s=0: item gate -> XXA5 rows + UAt      s=1: user gate -> FFA5 rows + IAu, SAu
#define LSTR 72  // padded LDS row stride in halves (144B)

__global__ __launch_bounds__(64) void k_tabs(
    const float* __restrict__ item_emb, const float* __restrict__ user_emb,
    const float* __restrict__ op_emb, const float* __restrict__ ia_Wg,
    const float* __restrict__ ia_bg, const float* __restrict__ ua_Wg,
    const float* __restrict__ ua_bg, const float* __restrict__ ia_Wa1,
    const float* __restrict__ ia_ba1, const float* __restrict__ sa_Wa1,
    const float* __restrict__ sa_ba1, const float* __restrict__ ua_Wa1,
    const float* __restrict__ ua_ba1, __half* __restrict__ XXA5,
    __half* __restrict__ FFA5, float* __restrict__ IAu,
    float* __restrict__ SAu, float* __restrict__ UAt, int NU_) {
  __shared__ _Float16 ldsX[16 * LSTR];
  __shared__ _Float16 ldsA[16 * LSTR];
  const int lane = threadIdx.x;
  const int nbl = NU_ >> 4;
  const int s = blockIdx.x / nbl, blk = blockIdx.x % nbl;
  const int g0 = blk * 16;
  const int q = lane >> 4, p = lane & 15;

  const float* emb = s ? user_emb : item_emb;
  const float* Wg = s ? ua_Wg : ia_Wg;
  const float* bg = s ? ua_bg : ia_bg;
  const float* Wa = s ? ua_Wa1 : ia_Wa1;  // low 64 rows
  __half* dst = s ? FFA5 : XXA5;

  // A-fragments of this block's 16 emb rows (shared by all outputs)
  half8 a0 = loadA_f32(emb + (size_t)g0 * D, 0, lane);
  half8 a1 = loadA_f32(emb + (size_t)g0 * D, 1, lane);

  // ---- fused extra outputs (share a0/a1) ----
  if (s == 0) {
#pragma unroll
    for (int t = 0; t < 4; ++t) {
      floatx4 acc = {0.f, 0.f, 0.f, 0.f};
      half8 b0 = loadB_f32(ua_Wa1 + D * D, 0, t, lane);
      half8 b1 = loadB_f32(ua_Wa1 + D * D, 1, t, lane);
      acc = __builtin_amdgcn_mfma_f32_16x16x32_f16(a0, b0, acc, 0, 0, 0);
      acc = __builtin_amdgcn_mfma_f32_16x16x32_f16(a1, b1, acc, 0, 0, 0);
      const float bv = ua_ba1[16 * t + p];
#pragma unroll
      for (int i = 0; i < 4; ++i)
        UAt[(size_t)(g0 + 4 * q + i) * D + 16 * t + p] = acc[i] + bv;
    }
  } else {
#pragma unroll
    for (int t = 0; t < 4; ++t) {
      floatx4 acc = {0.f, 0.f, 0.f, 0.f};
      half8 b0 = loadB_f32(ia_Wa1 + D * D, 0, t, lane);
      half8 b1 = loadB_f32(ia_Wa1 + D * D, 1, t, lane);
      acc = __builtin_amdgcn_mfma_f32_16x16x32_f16(a0, b0, acc, 0, 0, 0);
      acc = __builtin_amdgcn_mfma_f32_16x16x32_f16(a1, b1, acc, 0, 0, 0);
      const float bv = ia_ba1[16 * t + p];
#pragma unroll
      for (int i = 0; i < 4; ++i)
        IAu[(size_t)(g0 + 4 * q + i) * D + 16 * t + p] = acc[i] + bv;
    }
#pragma unroll
    for (int t = 0; t < 4; ++t) {
      floatx4 acc = {0.f, 0.f, 0.f, 0.f};
      half8 b0 = loadB_f32(sa_Wa1 + D * D, 0, t, lane);
      half8 b1 = loadB_f32(sa_Wa1 + D * D, 1, t, lane);
      acc = __builtin_amdgcn_mfma_f32_16x16x32_f16(a0, b0, acc, 0, 0, 0);
      acc = __builtin_amdgcn_mfma_f32_16x16x32_f16(a1, b1, acc, 0, 0, 0);
      const float bv = sa_ba1[16 * t + p];
#pragma unroll
      for (int i = 0; i < 4; ++i)
        SAu[(size_t)(g0 + 4 * q + i) * D + 16 * t + p] = acc[i] + bv;
    }
  }

  // ---- opbg[r] = bg + op_emb[r] @ Wg_hi  (per-lane d = lane) ----
  float opbg[5];
#pragma unroll
  for (int r = 0; r < 5; ++r) opbg[r] = bg[lane];
  for (int j = 0; j < D; ++j) {
    const float w = Wg[(size_t)(D + j) * D + lane];
#pragma unroll
    for (int r = 0; r < 5; ++r) opbg[r] = fmaf(op_emb[r * D + j], w, opbg[r]);
  }

  // ---- base = emb16x64 @ Wg_lo ; preload Wa B-frags ----
  floatx4 base[4];
  half8 wa[4][2];
#pragma unroll
  for (int t = 0; t < 4; ++t) {
    base[t] = {0.f, 0.f, 0.f, 0.f};
    half8 b0 = loadB_f32(Wg, 0, t, lane);
    half8 b1 = loadB_f32(Wg, 1, t, lane);
    base[t] = __builtin_amdgcn_mfma_f32_16x16x32_f16(a0, b0, base[t], 0, 0, 0);
    base[t] = __builtin_amdgcn_mfma_f32_16x16x32_f16(a1, b1, base[t], 0, 0, 0);
    wa[t][0] = loadB_f32(Wa, 0, t, lane);
    wa[t][1] = loadB_f32(Wa, 1, t, lane);
  }

  for (int r = 0; r < 5; ++r) {
    __syncthreads();  // prior iteration's ldsX/ldsA readers done
#pragma unroll
    for (int t = 0; t < 4; ++t) {
      const float ob = __shfl(opbg[r], p + 16 * t, 64);
#pragma unroll
      for (int i = 0; i < 4; ++i)
        ldsX[(4 * q + i) * LSTR + 16 * t + p] =
            (_Float16)fmaxf(base[t][i] + ob, 0.f);
    }
    __syncthreads();  // ldsX committed before cross-lane reads
    half8 xa0 = *(const half8*)&ldsX[p * LSTR + 0 * 32 + 8 * q];
    half8 xa1 = *(const half8*)&ldsX[p * LSTR + 1 * 32 + 8 * q];
    floatx4 acc[4];
#pragma unroll
    for (int t = 0; t < 4; ++t) {
      acc[t] = {0.f, 0.f, 0.f, 0.f};
      acc[t] = __builtin_amdgcn_mfma_f32_16x16x32_f16(xa0, wa[t][0], acc[t], 0,
                                                      0, 0);
      acc[t] = __builtin_amdgcn_mfma_f32_16x16x32_f16(xa1, wa[t][1], acc[t], 0,
                                                      0, 0);
    }
#pragma unroll
    for (int t = 0; t < 4; ++t)
#pragma unroll
      for (int i = 0; i < 4; ++i)
        ldsA[(4 * q + i) * LSTR + 16 * t + p] = (_Float16)acc[t][i];
    __syncthreads();  // ldsA/ldsX committed before type-punned uint reads
    const uint32_t* srcbuf =
        (lane < 32) ? (const uint32_t*)ldsA : (const uint32_t*)ldsX;
    const int dl = lane & 31;
    for (int m = 0; m < 16; ++m) {
      const uint32_t val = srcbuf[m * (LSTR / 2) + dl];
      uint32_t* rowp = (uint32_t*)(dst + ((size_t)(g0 + m) * 5 + r) * 128);
      rowp[lane] = val;
    }
  }
}

// ---------------- h_I_all: one wave per user, zero barriers ---------------------
__global__ __launch_bounds__(256, 8) void k_hIall(
    const int* __restrict__ C, const int* __restrict__ Rm,
    const __half* __restrict__ XXA5, const float* __restrict__ IAu,
    const float* __restrict__ ia_Wa2, const float* __restrict__ ia_W,
    const float* __restrict__ ia_b, const float* __restrict__ sa_Wa1,
    __half* __restrict__ HHA) {
  const int lane = threadIdx.x & 63;
  const int u = RFL(blockIdx.x * 4 + (threadIdx.x >> 6));
  const int kk = lane < KP ? lane : KP - 1;
  const int c = C[u * KP + kk];
  const int ix = c * 5 + Rm[(size_t)u * NIT + c];  // random HBM gather
  float sc = score_row_h(XXA5 + (size_t)ix * 128, IAu + (size_t)u * D, ia_Wa2);
  float a = softmax50(sc, lane);
  float v = wsum_rows_h(a, ix, XXA5, lane);
  float h = mv64b<true>(v, ia_W, ia_b, lane);
  float ha = 0.f;
#pragma unroll 8
  for (int j = 0; j < D; ++j)
    ha = fmaf(rlanef(h, j), sa_Wa1[j * D + lane], ha);
  HHA[(size_t)u * 128 + lane] = __float2half(ha);      // HA half (score)
  HHA[(size_t)u * 128 + 64 + lane] = __float2half(h);  // hI half (wsum/MLP)
}

// ---------------- batch: one wave per row, zero barriers ------------------------
__global__ __launch_bounds__(256, 8) void k_batch(
    const int* __restrict__ user_idx, const int* __restrict__ item_idx,
    const int* __restrict__ Nn, const int* __restrict__ Bm,
    const int* __restrict__ Rm, const __half* __restrict__ HHA,
    const __half* __restrict__ FFA5, const float* __restrict__ SAu,
    const float* __restrict__ UAt, const float* __restrict__ sa_Wa2,
    const float* __restrict__ sa_W, const float* __restrict__ sa_b,
    const float* __restrict__ ua_Wa2, const float* __restrict__ ua_W,
    const float* __restrict__ ua_b, const float* __restrict__ fu_W1,
    const float* __restrict__ fu_b1, const float* __restrict__ fu_W2,
    const float* __restrict__ fu_b2, const float* __restrict__ fu_W3,
    const float* __restrict__ fu_b3, const float* __restrict__ rp_W1,
    const float* __restrict__ rp_b1, const float* __restrict__ rp_W2,
    const float* __restrict__ rp_b2, const float* __restrict__ rp_W3,
    const float* __restrict__ rp_b3, float* __restrict__ out) {
  const int lane = threadIdx.x & 63;
  const int b = RFL(blockIdx.x * 4 + (threadIdx.x >> 6));
  const int u = RFL(user_idx[b]);
  const int it = RFL(item_idx[b]);
  const int kk = lane < KP ? lane : KP - 1;
  const int nix = Nn[u * KP + kk];
  const int bn = Bm[it * KP + kk];
  const int ix2 = bn * 5 + Rm[(size_t)bn * NIT + it];
  const float hIu = (float)HHA[(size_t)u * 128 + 64 + lane];
  // ---- phase S ----
  float sc = score_row_h(HHA + (size_t)nix * 128, SAu + (size_t)u * D, sa_Wa2);
  float a = softmax50(sc, lane);
  float v = wsum_rows_h(a, nix, HHA, lane);
  float hS = mv64b<true>(v, sa_W, sa_b, lane);
  // ---- phase Z ----
  float sc2 =
      score_row_h(FFA5 + (size_t)ix2 * 128, UAt + (size_t)it * D, ua_Wa2);
  float a2 = softmax50(sc2, lane);
  float v2 = wsum_rows_h(a2, ix2, FFA5, lane);
  float z = mv64b<true>(v2, ua_W, ua_b, lane);
  // ---- fu MLP ----
  float h = mv128b(hIu, hS, fu_W1, fu_b1, lane);
  h = mv64b<true>(h, fu_W2, fu_b2, lane);
  h = mv64b<true>(h, fu_W3, fu_b3, lane);
  // ---- rp MLP ----
  float g = mv128b(h, z, rp_W1, rp_b1, lane);
  g = mv64b<true>(g, rp_W2, rp_b2, lane);
  float pp = g * rp_W3[lane];
#pragma unroll
  for (int o = 1; o < 64; o <<= 1) pp += __shfl_xor(pp, o, 64);
  if (lane == 0) out[b] = pp + rp_b3[0];
}

extern "C" void kernel_launch(void* const* d_in, const int* in_sizes, int n_in,
                              void* d_out, int out_size, void* d_ws,
                              size_t ws_size, hipStream_t stream) {
  const int* user_idx = (const int*)d_in[0];
  const int* item_idx = (const int*)d_in[1];
  const int* C = (const int*)d_in[2];
  const int* Nn = (const int*)d_in[3];
  const int* Bm = (const int*)d_in[4];
  const int* Rm = (const int*)d_in[5];
  const float* user_emb = (const float*)d_in[6];
  const float* item_emb = (const float*)d_in[7];
  const float* opinion_emb = (const float*)d_in[8];
  const float* ia_Wg = (const float*)d_in[9];
  const float* ia_bg = (const float*)d_in[10];
  const float* ua_Wg = (const float*)d_in[11];
  const float* ua_bg = (const float*)d_in[12];
  const float* ia_Wa1 = (const float*)d_in[13];
  const float* ia_ba1 = (const float*)d_in[14];
  const float* ia_Wa2 = (const float*)d_in[15];
  const float* ia_W = (const float*)d_in[17];
  const float* ia_b = (const float*)d_in[18];
  const float* sa_Wa1 = (const float*)d_in[19];
  const float* sa_ba1 = (const float*)d_in[20];
  const float* sa_Wa2 = (const float*)d_in[21];
  const float* sa_W = (const float*)d_in[23];
  const float* sa_b = (const float*)d_in[24];
  const float* ua_Wa1 = (const float*)d_in[25];
  const float* ua_ba1 = (const float*)d_in[26];
  const float* ua_Wa2 = (const float*)d_in[27];
  const float* ua_W = (const float*)d_in[29];
  const float* ua_b = (const float*)d_in[30];
  const float* fu_W1 = (const float*)d_in[31];
  const float* fu_b1 = (const float*)d_in[32];
  const float* fu_W2 = (const float*)d_in[33];
  const float* fu_b2 = (const float*)d_in[34];
  const float* rp_W1 = (const float*)d_in[35];
  const float* rp_b1 = (const float*)d_in[36];
  const float* rp_W2 = (const float*)d_in[37];
  const float* rp_b2 = (const float*)d_in[38];
  const float* fu_W3 = (const float*)d_in[39];
  const float* fu_b3 = (const float*)d_in[40];
  const float* rp_W3 = (const float*)d_in[41];
  const float* rp_b3 = (const float*)d_in[42];

  const int NU = in_sizes[6] / D;  // 10000 users
  const int B = in_sizes[0];       // 2048

  __half* XXA5 = (__half*)d_ws;                   // NU*5*128 halves
  __half* FFA5 = XXA5 + (size_t)NU * 5 * 128;     // NU*5*128 halves
  __half* HHA = FFA5 + (size_t)NU * 5 * 128;      // NU*128 halves
  float* IAu = (float*)(HHA + (size_t)NU * 128);  // NU*D fp32
  float* SAu = IAu + (size_t)NU * D;
  float* UAt = SAu + (size_t)NU * D;

  const int nbl = NU / 16;  // 625

  k_tabs<<<2 * nbl, 64, 0, stream>>>(item_emb, user_emb, opinion_emb, ia_Wg,
                                     ia_bg, ua_Wg, ua_bg, ia_Wa1, ia_ba1,
                                     sa_Wa1, sa_ba1, ua_Wa1, ua_ba1, XXA5,
                                     FFA5, IAu, SAu, UAt, NU);
  k_hIall<<<NU / 4, 256, 0, stream>>>(C, Rm, XXA5, IAu, ia_Wa2, ia_W, ia_b,
                                      sa_Wa1, HHA);
  k_batch<<<B / 4, 256, 0, stream>>>(user_idx, item_idx, Nn, Bm, Rm, HHA, FFA5,
                                     SAu, UAt, sa_Wa2, sa_W, sa_b, ua_Wa2,
                                     ua_W, ua_b, fu_W1, fu_b1, fu_W2, fu_b2,
                                     fu_W3, fu_b3, rp_W1, rp_b1, rp_W2, rp_b2,
                                     rp_W3, rp_b3, (float*)d_out);
}